// Round 2
// baseline (661.853 us; speedup 1.0000x reference)
//
#include <hip/hip_runtime.h>
#include <math.h>

#define B_ 256
#define L_ 100
#define H_ 8
#define E_ 64
#define D_ 64

// Output offsets (floats), concatenated in reference return order:
// V[B,L,H,D], series[B,H,L,L], prior[B,H,L,L], sig[B,H,L,L], M[B,H,L]
#define OFF_SERIES ((size_t)B_ * L_ * H_ * D_)          // 13107200
#define OFF_PRIOR  (OFF_SERIES + (size_t)B_ * H_ * L_ * L_)
#define OFF_SIG    (OFF_PRIOR  + (size_t)B_ * H_ * L_ * L_)
#define OFF_M      (OFF_SIG    + (size_t)B_ * H_ * L_ * L_)

#define LOG2E 1.4426950408889634f
#define LN3   1.0986122886681098f
#define INV_SQRT_2PI 0.3989422804014327f

// ---------------- Kernel A: prior + sig ----------------
__global__ __launch_bounds__(256) void prior_kernel(
    const float* __restrict__ sigma, const float* __restrict__ dist,
    float* __restrict__ prior, float* __restrict__ sigout) {
    const int bid = blockIdx.x;
    const int b = bid >> 3, h = bid & 7;
    __shared__ float sg[L_];
    const int t = threadIdx.x;
    if (t < L_) {
        float x = sigma[((size_t)b * L_ + t) * H_ + h];
        float s = 1.0f / (1.0f + exp2f(-5.0f * LOG2E * x)) + 1e-5f;
        sg[t] = expm1f(s * LN3);   // 3^s - 1, accurate near 0
    }
    __syncthreads();
    const size_t base = (size_t)(b * H_ + h) * (L_ * L_);
    for (int idx = t; idx < L_ * L_; idx += 256) {
        int l = idx / L_;
        float sgm = sg[l];
        float d = dist[idx];
        float inv_s = 1.0f / sgm;
        float pr = INV_SQRT_2PI * inv_s *
                   exp2f(-0.5f * LOG2E * d * d * inv_s * inv_s);
        prior[base + idx]  = pr;
        sigout[base + idx] = sgm;
    }
}

// ---------------- Kernel B: scores -> series, M ----------------
// One block per (b,h), 4 waves, each wave owns 25 query rows, processed in
// 5 passes of R=5 rows. Each KT4 fragment read from LDS feeds 5 rows' FMAs
// (5x less LDS traffic than R=1), and the 5 rows' wave reductions are
// independent -> shuffle latency hidden by ILP.
// K staged transposed as float4 [e4][j] with XOR swizzle (j ^ (e4&7)),
// j padded to 128 with zero rows. Lane j holds score slots j and j+64.
__global__ __launch_bounds__(256) void scores_kernel(
    const float* __restrict__ Q, const float* __restrict__ K,
    float* __restrict__ series, float* __restrict__ Mout) {
    const int bid = blockIdx.x;
    const int b = bid >> 3, h = bid & 7;
    __shared__ float4 KT4[16 * 128];  // 32 KB
    const int t = threadIdx.x;
    for (int f = t; f < 16 * 128; f += 256) {
        int j = f >> 4, e4 = f & 15;
        float4 v = make_float4(0.f, 0.f, 0.f, 0.f);
        if (j < L_)
            v = *(const float4*)(K + (((size_t)b * L_ + j) * H_ + h) * E_ + e4 * 4);
        KT4[e4 * 128 + (j ^ (e4 & 7))] = v;
    }
    __syncthreads();

    const int wave = __builtin_amdgcn_readfirstlane(t >> 6);
    const int lane = t & 63;
    const int j2 = lane + 64;
    const bool valid1 = (j2 < L_);  // lane < 36

    for (int i0 = 0; i0 < 25; i0 += 5) {
        const int l0 = wave * 25 + i0;
        const float* q0 = Q + (((size_t)b * L_ + l0) * H_ + h) * E_;
        float s0[5] = {0.f, 0.f, 0.f, 0.f, 0.f};
        float s1[5] = {0.f, 0.f, 0.f, 0.f, 0.f};
#pragma unroll
        for (int e4 = 0; e4 < 16; ++e4) {
            float4 ka = KT4[e4 * 128 + (lane ^ (e4 & 7))];
            float4 kb = KT4[e4 * 128 + (j2 ^ (e4 & 7))];
#pragma unroll
            for (int r = 0; r < 5; ++r) {
                // wave-uniform -> s_load_dwordx4 (no VGPR cost)
                float4 q = *(const float4*)(q0 + r * (H_ * E_) + e4 * 4);
                s0[r] += q.x * ka.x + q.y * ka.y + q.z * ka.z + q.w * ka.w;
                s1[r] += q.x * kb.x + q.y * kb.y + q.z * kb.z + q.w * kb.w;
            }
        }
        // ---- row statistics over the 100 real j slots ----
        float m1[5], m2[5], sum1[5], sum2[5];
#pragma unroll
        for (int r = 0; r < 5; ++r) {
            const int l = l0 + r;
            m1[r]   = valid1 ? fmaxf(s0[r], s1[r]) : s0[r];
            sum1[r] = valid1 ? (s0[r] + s1[r]) : s0[r];
            int d0 = l - lane;  bool band0 = (d0 < 3) && (d0 > -3);
            int d1 = l - j2;    bool band1 = (d1 < 3) && (d1 > -3);
            float sp0 = band0 ? 0.f : s0[r];
            float sp1 = (valid1 && !band1) ? s1[r] : 0.f;
            m2[r]   = fmaxf(sp0, sp1);
            sum2[r] = sp0 + sp1;
        }
        // interleaved wave reductions: 20 independent chains per step
#pragma unroll
        for (int off = 32; off > 0; off >>= 1) {
#pragma unroll
            for (int r = 0; r < 5; ++r) {
                m1[r]   = fmaxf(m1[r], __shfl_xor(m1[r], off, 64));
                m2[r]   = fmaxf(m2[r], __shfl_xor(m2[r], off, 64));
                sum1[r] += __shfl_xor(sum1[r], off, 64);
                sum2[r] += __shfl_xor(sum2[r], off, 64);
            }
        }
        // ---- softmax over attn = scale * scores ----
        const float c = 0.125f * LOG2E;
        float p0[5], p1[5], den[5];
#pragma unroll
        for (int r = 0; r < 5; ++r) {
            p0[r] = exp2f((s0[r] - m1[r]) * c);
            p1[r] = valid1 ? exp2f((s1[r] - m1[r]) * c) : 0.f;
            den[r] = p0[r] + p1[r];
        }
#pragma unroll
        for (int off = 32; off > 0; off >>= 1)
#pragma unroll
            for (int r = 0; r < 5; ++r)
                den[r] += __shfl_xor(den[r], off, 64);
#pragma unroll
        for (int r = 0; r < 5; ++r) {
            const int l = l0 + r;
            float inv = 1.0f / den[r];
            float se0 = (lane == l) ? 0.f : p0[r] * inv;
            float se1 = (j2  == l) ? 0.f : p1[r] * inv;
            const size_t rowoff = ((size_t)(b * H_ + h) * L_ + l) * L_;
            series[rowoff + lane] = se0;
            if (valid1) series[rowoff + j2] = se1;
            if (lane == 0) {
                float M1 = m1[r] - sum1[r] * (1.0f / 100.0f);
                float M2 = m2[r] - sum2[r] * (1.0f / 94.0f);
                Mout[(size_t)(b * H_ + h) * L_ + l] = M1 - M2;
            }
        }
    }
}

// ---------------- Kernel C: V = series @ values ----------------
__global__ __launch_bounds__(256) void pv_kernel(
    const float* __restrict__ Vin, const float* __restrict__ series,
    float* __restrict__ Vout) {
    const int bid = blockIdx.x;
    const int b = bid >> 3, h = bid & 7;
    __shared__ float Vl[L_ * D_];  // 25.6 KB
    const int t = threadIdx.x;
    for (int f = t; f < L_ * 16; f += 256) {
        int j = f >> 4, q = f & 15;
        *(float4*)(Vl + j * D_ + q * 4) =
            *(const float4*)(Vin + (((size_t)b * L_ + j) * H_ + h) * D_ + q * 4);
    }
    __syncthreads();

    const int wave = __builtin_amdgcn_readfirstlane(t >> 6);
    const int lane = t & 63;  // = d

    for (int i0 = 0; i0 < 25; i0 += 5) {
        const int l0 = wave * 25 + i0;
        const float* prow = series + ((size_t)(b * H_ + h) * L_ + l0) * L_;
        float acc0 = 0.f, acc1 = 0.f, acc2 = 0.f, acc3 = 0.f, acc4 = 0.f;
#pragma unroll 4
        for (int j = 0; j < L_; ++j) {
            float v = Vl[j * D_ + lane];
            acc0 += prow[0 * L_ + j] * v;   // wave-uniform -> s_load
            acc1 += prow[1 * L_ + j] * v;
            acc2 += prow[2 * L_ + j] * v;
            acc3 += prow[3 * L_ + j] * v;
            acc4 += prow[4 * L_ + j] * v;
        }
        Vout[(((size_t)b * L_ + (l0 + 0)) * H_ + h) * D_ + lane] = acc0;
        Vout[(((size_t)b * L_ + (l0 + 1)) * H_ + h) * D_ + lane] = acc1;
        Vout[(((size_t)b * L_ + (l0 + 2)) * H_ + h) * D_ + lane] = acc2;
        Vout[(((size_t)b * L_ + (l0 + 3)) * H_ + h) * D_ + lane] = acc3;
        Vout[(((size_t)b * L_ + (l0 + 4)) * H_ + h) * D_ + lane] = acc4;
    }
}

extern "C" void kernel_launch(void* const* d_in, const int* in_sizes, int n_in,
                              void* d_out, int out_size, void* d_ws, size_t ws_size,
                              hipStream_t stream) {
    const float* Q     = (const float*)d_in[0];
    const float* K     = (const float*)d_in[1];
    const float* V     = (const float*)d_in[2];
    const float* sigma = (const float*)d_in[3];
    const float* dist  = (const float*)d_in[4];

    float* out    = (float*)d_out;
    float* Vout   = out;
    float* series = out + OFF_SERIES;
    float* prior  = out + OFF_PRIOR;
    float* sigout = out + OFF_SIG;
    float* Mout   = out + OFF_M;

    dim3 grid(B_ * H_), block(256);
    hipLaunchKernelGGL(prior_kernel,  grid, block, 0, stream, sigma, dist, prior, sigout);
    hipLaunchKernelGGL(scores_kernel, grid, block, 0, stream, Q, K, series, Mout);
    hipLaunchKernelGGL(pv_kernel,     grid, block, 0, stream, V, series, Vout);
}

// Round 3
// 474.321 us; speedup vs baseline: 1.3954x; 1.3954x over previous
//
#include <hip/hip_runtime.h>
#include <math.h>

#define B_ 256
#define L_ 100
#define H_ 8
#define E_ 64
#define D_ 64

// Output offsets (floats), concatenated in reference return order:
// V[B,L,H,D], series[B,H,L,L], prior[B,H,L,L], sig[B,H,L,L], M[B,H,L]
#define OFF_SERIES ((size_t)B_ * L_ * H_ * D_)
#define OFF_PRIOR  (OFF_SERIES + (size_t)B_ * H_ * L_ * L_)
#define OFF_SIG    (OFF_PRIOR  + (size_t)B_ * H_ * L_ * L_)
#define OFF_M      (OFF_SIG    + (size_t)B_ * H_ * L_ * L_)

#define LOG2E 1.4426950408889634f
#define LN3   1.0986122886681098f
#define INV_SQRT_2PI 0.3989422804014327f

// ---------------- Kernel A: prior + sig ----------------
// Per-row constants precomputed once; float4 elementwise over the 100x100
// tile (100 % 4 == 0 so float4 never crosses a row). HBM-bound.
__global__ __launch_bounds__(256) void prior_kernel(
    const float* __restrict__ sigma, const float* __restrict__ dist,
    float* __restrict__ prior, float* __restrict__ sigout) {
    const int bid = blockIdx.x;
    const int b = bid >> 3, h = bid & 7;
    __shared__ float sgs[L_], c1s[L_], c2s[L_];
    const int t = threadIdx.x;
    if (t < L_) {
        float x = sigma[((size_t)b * L_ + t) * H_ + h];
        float s = 1.0f / (1.0f + exp2f(-5.0f * LOG2E * x)) + 1e-5f;
        float sg = expm1f(s * LN3);          // 3^s - 1, accurate near 0
        float inv = 1.0f / sg;
        sgs[t] = sg;
        c1s[t] = INV_SQRT_2PI * inv;
        c2s[t] = 0.5f * LOG2E * inv * inv;
    }
    __syncthreads();
    const size_t base4 = (size_t)(b * H_ + h) * (L_ * L_ / 4);
    const float4* d4 = (const float4*)dist;
    float4* p4 = (float4*)prior;
    float4* s4 = (float4*)sigout;
    for (int idx = t; idx < L_ * L_ / 4; idx += 256) {
        int l = idx / (L_ / 4);
        float c1 = c1s[l], c2 = c2s[l], sg = sgs[l];
        float4 d = d4[idx];
        float4 pr;
        pr.x = c1 * exp2f(-d.x * d.x * c2);
        pr.y = c1 * exp2f(-d.y * d.y * c2);
        pr.z = c1 * exp2f(-d.z * d.z * c2);
        pr.w = c1 * exp2f(-d.w * d.w * c2);
        p4[base4 + idx] = pr;
        s4[base4 + idx] = make_float4(sg, sg, sg, sg);
    }
}

// ---------------- Kernel B: scores -> series, M ----------------
// One block per (b,h), 4 waves x 25 rows, 5 rows per pass.
// K transposed in LDS [e4][j] pad 105 (reads lane->j consecutive, conflict-
// free; j>=100 rows zeroed). Q staged in LDS, read as same-address
// broadcasts (no SMEM/DS lgkmcnt mixing!). Softmax without max-subtract
// (shift-invariant; |s*scale| small) so all 5 stats reduce in ONE
// interleaved 6-step shuffle block per pass.
__global__ __launch_bounds__(256) void scores_kernel(
    const float* __restrict__ Q, const float* __restrict__ K,
    float* __restrict__ series, float* __restrict__ Mout) {
    const int bid = blockIdx.x;
    const int b = bid >> 3, h = bid & 7;
    __shared__ float4 KT4[16 * 105];  // 26880 B
    __shared__ float4 Ql[L_ * 16];    // 25600 B
    const int t = threadIdx.x;
    for (int f = t; f < L_ * 16; f += 256) {
        int j = f >> 4, e4 = f & 15;
        KT4[e4 * 105 + j] = *(const float4*)(K + (((size_t)b * L_ + j) * H_ + h) * E_ + e4 * 4);
        Ql[f] = *(const float4*)(Q + (((size_t)b * L_ + j) * H_ + h) * E_ + e4 * 4);
    }
    if (t < 80) {  // zero pad rows j = 100..104
        int e4 = t / 5, jp = 100 + t % 5;
        KT4[e4 * 105 + jp] = make_float4(0.f, 0.f, 0.f, 0.f);
    }
    __syncthreads();

    const int wave = __builtin_amdgcn_readfirstlane(t >> 6);
    const int lane = t & 63;
    const int j2 = lane + 64;
    const bool valid1 = (j2 < L_);           // lane < 36
    const int j2c = (j2 < 105) ? j2 : 104;   // clamp into zero-pad rows

    for (int i0 = 0; i0 < 25; i0 += 5) {
        const int l0 = wave * 25 + i0;
        float s0[5] = {0.f, 0.f, 0.f, 0.f, 0.f};
        float s1[5] = {0.f, 0.f, 0.f, 0.f, 0.f};
#pragma unroll
        for (int e4 = 0; e4 < 16; ++e4) {
            float4 ka = KT4[e4 * 105 + lane];
            float4 kb = KT4[e4 * 105 + j2c];
#pragma unroll
            for (int r = 0; r < 5; ++r) {
                float4 q = Ql[(l0 + r) * 16 + e4];  // LDS broadcast
                s0[r] += q.x * ka.x + q.y * ka.y + q.z * ka.z + q.w * ka.w;
                s1[r] += q.x * kb.x + q.y * kb.y + q.z * kb.z + q.w * kb.w;
            }
        }
        // ---- per-lane stats + unnormalized softmax terms ----
        const float c = 0.125f * LOG2E;
        float m1[5], m2[5], sum1[5], sum2[5], den[5], p0[5], p1[5];
#pragma unroll
        for (int r = 0; r < 5; ++r) {
            const int l = l0 + r;
            m1[r]   = valid1 ? fmaxf(s0[r], s1[r]) : s0[r];
            sum1[r] = valid1 ? (s0[r] + s1[r]) : s0[r];
            int d0 = l - lane;  bool band0 = (d0 < 3) && (d0 > -3);
            int d1 = l - j2;    bool band1 = (d1 < 3) && (d1 > -3);
            float sp0 = band0 ? 0.f : s0[r];
            float sp1 = (valid1 && !band1) ? s1[r] : 0.f;
            m2[r]   = fmaxf(sp0, sp1);
            sum2[r] = sp0 + sp1;
            p0[r] = exp2f(s0[r] * c);
            p1[r] = valid1 ? exp2f(s1[r] * c) : 0.f;
            den[r] = p0[r] + p1[r];
        }
        // ---- ONE interleaved reduction block: 25 independent chains ----
#pragma unroll
        for (int off = 32; off > 0; off >>= 1) {
#pragma unroll
            for (int r = 0; r < 5; ++r) {
                m1[r]   = fmaxf(m1[r], __shfl_xor(m1[r], off, 64));
                m2[r]   = fmaxf(m2[r], __shfl_xor(m2[r], off, 64));
                sum1[r] += __shfl_xor(sum1[r], off, 64);
                sum2[r] += __shfl_xor(sum2[r], off, 64);
                den[r]  += __shfl_xor(den[r], off, 64);
            }
        }
#pragma unroll
        for (int r = 0; r < 5; ++r) {
            const int l = l0 + r;
            float inv = 1.0f / den[r];
            float se0 = (lane == l) ? 0.f : p0[r] * inv;
            float se1 = (j2  == l) ? 0.f : p1[r] * inv;
            const size_t rowoff = ((size_t)(b * H_ + h) * L_ + l) * L_;
            series[rowoff + lane] = se0;
            if (valid1) series[rowoff + j2] = se1;
            if (lane == 0) {
                float M1 = m1[r] - sum1[r] * (1.0f / 100.0f);
                float M2 = m2[r] - sum2[r] * (1.0f / 94.0f);
                Mout[(size_t)(b * H_ + h) * L_ + l] = M1 - M2;
            }
        }
    }
}

// ---------------- Kernel C: V = series @ values ----------------
// Both operands staged in LDS: V [j][d] (per-lane b32, conflict-free),
// series tile (broadcast float4 reads). No SMEM/DS mixing.
__global__ __launch_bounds__(256) void pv_kernel(
    const float* __restrict__ Vin, const float* __restrict__ series,
    float* __restrict__ Vout) {
    const int bid = blockIdx.x;
    const int b = bid >> 3, h = bid & 7;
    __shared__ float Vl[L_ * D_];    // 25600 B
    __shared__ float Sl[L_ * L_];    // 40000 B
    const int t = threadIdx.x;
    for (int f = t; f < L_ * 16; f += 256) {
        int j = f >> 4, q = f & 15;
        *(float4*)(Vl + j * D_ + q * 4) =
            *(const float4*)(Vin + (((size_t)b * L_ + j) * H_ + h) * D_ + q * 4);
    }
    const float4* srow4 = (const float4*)(series + (size_t)(b * H_ + h) * (L_ * L_));
    for (int f = t; f < L_ * L_ / 4; f += 256)
        *(float4*)(Sl + f * 4) = srow4[f];
    __syncthreads();

    const int wave = __builtin_amdgcn_readfirstlane(t >> 6);
    const int lane = t & 63;  // = d

    for (int i0 = 0; i0 < 25; i0 += 5) {
        const int l0 = wave * 25 + i0;
        float acc[5] = {0.f, 0.f, 0.f, 0.f, 0.f};
#pragma unroll 5
        for (int jb = 0; jb < 25; ++jb) {
            float v0 = Vl[(jb * 4 + 0) * D_ + lane];
            float v1 = Vl[(jb * 4 + 1) * D_ + lane];
            float v2 = Vl[(jb * 4 + 2) * D_ + lane];
            float v3 = Vl[(jb * 4 + 3) * D_ + lane];
#pragma unroll
            for (int r = 0; r < 5; ++r) {
                float4 p = *(const float4*)(Sl + (l0 + r) * L_ + jb * 4);  // broadcast
                acc[r] += p.x * v0 + p.y * v1 + p.z * v2 + p.w * v3;
            }
        }
#pragma unroll
        for (int r = 0; r < 5; ++r)
            Vout[(((size_t)b * L_ + (l0 + r)) * H_ + h) * D_ + lane] = acc[r];
    }
}

extern "C" void kernel_launch(void* const* d_in, const int* in_sizes, int n_in,
                              void* d_out, int out_size, void* d_ws, size_t ws_size,
                              hipStream_t stream) {
    const float* Q     = (const float*)d_in[0];
    const float* K     = (const float*)d_in[1];
    const float* V     = (const float*)d_in[2];
    const float* sigma = (const float*)d_in[3];
    const float* dist  = (const float*)d_in[4];

    float* out    = (float*)d_out;
    float* Vout   = out;
    float* series = out + OFF_SERIES;
    float* prior  = out + OFF_PRIOR;
    float* sigout = out + OFF_SIG;
    float* Mout   = out + OFF_M;

    dim3 grid(B_ * H_), block(256);
    hipLaunchKernelGGL(prior_kernel,  grid, block, 0, stream, sigma, dist, prior, sigout);
    hipLaunchKernelGGL(scores_kernel, grid, block, 0, stream, Q, K, series, Mout);
    hipLaunchKernelGGL(pv_kernel,     grid, block, 0, stream, V, series, Vout);
}

// Round 4
// 263.806 us; speedup vs baseline: 2.5089x; 1.7980x over previous
//
#include <hip/hip_runtime.h>
#include <math.h>

#define B_ 256
#define L_ 100
#define H_ 8
#define E_ 64
#define D_ 64

// Output offsets (floats), concatenated in reference return order:
// V[B,L,H,D], series[B,H,L,L], prior[B,H,L,L], sig[B,H,L,L], M[B,H,L]
#define OFF_SERIES ((size_t)B_ * L_ * H_ * D_)
#define OFF_PRIOR  (OFF_SERIES + (size_t)B_ * H_ * L_ * L_)
#define OFF_SIG    (OFF_PRIOR  + (size_t)B_ * H_ * L_ * L_)
#define OFF_M      (OFF_SIG    + (size_t)B_ * H_ * L_ * L_)

#define LOG2E 1.4426950408889634f
#define LN3   1.0986122886681098f
#define INV_SQRT_2PI 0.3989422804014327f

typedef __attribute__((ext_vector_type(8))) short short8b;  // 8 bf16 (4 VGPRs)
typedef __attribute__((ext_vector_type(4))) float f32x4;

// ---------------- Kernel A: prior + sig ----------------
__global__ __launch_bounds__(256) void prior_kernel(
    const float* __restrict__ sigma, const float* __restrict__ dist,
    float* __restrict__ prior, float* __restrict__ sigout) {
    const int bid = blockIdx.x;
    const int b = bid >> 3, h = bid & 7;
    __shared__ float sgs[L_], c1s[L_], c2s[L_];
    const int t = threadIdx.x;
    if (t < L_) {
        float x = sigma[((size_t)b * L_ + t) * H_ + h];
        float s = 1.0f / (1.0f + exp2f(-5.0f * LOG2E * x)) + 1e-5f;
        float sg = expm1f(s * LN3);          // 3^s - 1, accurate near 0
        float inv = 1.0f / sg;
        sgs[t] = sg;
        c1s[t] = INV_SQRT_2PI * inv;
        c2s[t] = 0.5f * LOG2E * inv * inv;
    }
    __syncthreads();
    const size_t base4 = (size_t)(b * H_ + h) * (L_ * L_ / 4);
    const float4* d4 = (const float4*)dist;
    float4* p4 = (float4*)prior;
    float4* s4 = (float4*)sigout;
    for (int idx = t; idx < L_ * L_ / 4; idx += 256) {
        int l = idx / (L_ / 4);
        float c1 = c1s[l], c2 = c2s[l], sg = sgs[l];
        float4 d = d4[idx];
        float4 pr;
        pr.x = c1 * exp2f(-d.x * d.x * c2);
        pr.y = c1 * exp2f(-d.y * d.y * c2);
        pr.z = c1 * exp2f(-d.z * d.z * c2);
        pr.w = c1 * exp2f(-d.w * d.w * c2);
        p4[base4 + idx] = pr;
        s4[base4 + idx] = make_float4(sg, sg, sg, sg);
    }
}

// ---------------- Kernel B: scores via MFMA (S^T = K.Q^T) ----------------
// Split-bf16: f32 a ~= hi + lo (bf16 each); a*b ~= ah*bh + ah*bl + al*bh
// (error ~2^-16 relative). MFMA 16x16x32 with A=K rows(j), B=Q^T cols(l):
// D layout (m89): col l = lane&15, row j = jt*16 + (lane>>4)*4 + reg.
// All row-stats are lane-local over regs/jt, finalized with TWO shfl_xor
// steps (16, 32). P staged unnormalized in LDS (aliases dead Q region),
// normalized by 1/den during coalesced float4 copy-out; diag pre-zeroed.
// LDS: Khi@0, Klo@12800, Qhi@25600, Qlo@38400 (each 12800 B, ushort,
// byte ^= (row&7)<<4 swizzle); P region = 25600..51200 (4 waves x [16][100] f32);
// den_s @ 51200 (64 f32).
__global__ __launch_bounds__(256) void scores_kernel(
    const float* __restrict__ Q, const float* __restrict__ K,
    float* __restrict__ series, float* __restrict__ Mout) {
    const int bid = blockIdx.x;
    const int b = bid >> 3, h = bid & 7;
    __shared__ __align__(16) char smem[51456];
    float* den_s = (float*)(smem + 51200);
    const int t = threadIdx.x;

    // ---- stage Q, K as bf16 hi/lo (XOR-swizzled rows) ----
    for (int pass = 0; pass < 2; ++pass) {
        const float* Mt = pass ? K : Q;
        const int hioff = pass ? 0 : 25600;
        const int looff = pass ? 12800 : 38400;
        for (int ci = t; ci < 800; ci += 256) {
            int row = ci >> 3, c8 = ci & 7;
            const float* src = Mt + ((size_t)(b * L_ + row) * H_ + h) * E_ + c8 * 8;
            float4 f0 = *(const float4*)src;
            float4 f1 = *(const float4*)(src + 4);
            float f[8] = {f0.x, f0.y, f0.z, f0.w, f1.x, f1.y, f1.z, f1.w};
            short8b hi8, lo8;
#pragma unroll
            for (int i = 0; i < 8; ++i) {
                unsigned u = __float_as_uint(f[i]);
                hi8[i] = (short)(u >> 16);
                float r = f[i] - __uint_as_float(u & 0xFFFF0000u);
                lo8[i] = (short)(__float_as_uint(r) >> 16);
            }
            int byte = (row * 128 + c8 * 16) ^ ((row & 7) << 4);
            *(short8b*)(smem + hioff + byte) = hi8;
            *(short8b*)(smem + looff + byte) = lo8;
        }
    }
    __syncthreads();

    const int wave = t >> 6;
    const int lane = t & 63;
    const int lr = lane & 15;   // tile row (P) / matrix col l-offset
    const int g  = lane >> 4;   // k-group

    // ---- B-frags (Q^T) for this wave's l-tiles; then Q region is dead ----
    const int nt = (wave < 3) ? 2 : 1;
    short8b qh[2][2], ql[2][2];
    for (int ti = 0; ti < nt; ++ti) {
        int lt = wave * 2 + ti;
        int lrow = lt * 16 + lr; if (lrow > 99) lrow = 99;
        int rb = lrow * 128, sw = (lrow & 7) << 4;
#pragma unroll
        for (int es = 0; es < 2; ++es) {
            int byte = (rb + g * 16 + es * 64) ^ sw;
            qh[ti][es] = *(const short8b*)(smem + 25600 + byte);
            ql[ti][es] = *(const short8b*)(smem + 38400 + byte);
        }
    }
    __syncthreads();   // all B-frags loaded -> P staging may reuse Q region

    const float cs = 0.125f * LOG2E;
    const size_t bh = (size_t)(b * H_ + h);
    char* pbase = smem + 25600 + wave * 6400;   // [16][100] f32 per wave

    for (int ti = 0; ti < nt; ++ti) {
        const int lt = wave * 2 + ti;
        const int l = lt * 16 + lr;     // this lane's column (may be >=100)
        float m1 = -INFINITY, m2 = -INFINITY, sum1 = 0.f, sum2 = 0.f, den = 0.f;
        for (int jt = 0; jt < 7; ++jt) {
            int jrow = jt * 16 + lr; if (jrow > 99) jrow = 99;
            int rb = jrow * 128, sw = (jrow & 7) << 4;
            f32x4 C = {0.f, 0.f, 0.f, 0.f};
#pragma unroll
            for (int es = 0; es < 2; ++es) {
                int byte = (rb + g * 16 + es * 64) ^ sw;
                short8b kh = *(const short8b*)(smem + 0 + byte);
                short8b kl = *(const short8b*)(smem + 12800 + byte);
                C = __builtin_amdgcn_mfma_f32_16x16x32_bf16(kh, qh[ti][es], C, 0, 0, 0);
                C = __builtin_amdgcn_mfma_f32_16x16x32_bf16(kh, ql[ti][es], C, 0, 0, 0);
                C = __builtin_amdgcn_mfma_f32_16x16x32_bf16(kl, qh[ti][es], C, 0, 0, 0);
            }
            f32x4 pw = {0.f, 0.f, 0.f, 0.f};
#pragma unroll
            for (int r = 0; r < 4; ++r) {
                int j = jt * 16 + g * 4 + r;
                float s = C[r];
                if (j < 100) {
                    m1 = fmaxf(m1, s);
                    sum1 += s;
                    bool band = (j - l < 3) && (l - j < 3);
                    float sp = band ? 0.f : s;
                    m2 = fmaxf(m2, sp);
                    sum2 += sp;
                    float p = exp2f(s * cs);
                    den += p;                       // diag included in den
                    pw[r] = (j == l) ? 0.f : p;     // diag zeroed in output
                }
            }
            if (!(jt == 6 && g > 0))
                *(f32x4*)(pbase + lr * 400 + jt * 64 + g * 16) = pw;
        }
        // finalize stats: combine the 4 k-groups (lanes ^16, ^32)
        m1   = fmaxf(m1, __shfl_xor(m1, 16, 64));
        m1   = fmaxf(m1, __shfl_xor(m1, 32, 64));
        m2   = fmaxf(m2, __shfl_xor(m2, 16, 64));
        m2   = fmaxf(m2, __shfl_xor(m2, 32, 64));
        sum1 += __shfl_xor(sum1, 16, 64);
        sum1 += __shfl_xor(sum1, 32, 64);
        sum2 += __shfl_xor(sum2, 16, 64);
        sum2 += __shfl_xor(sum2, 32, 64);
        den  += __shfl_xor(den, 16, 64);
        den  += __shfl_xor(den, 32, 64);
        if (lane < 16 && l < 100) {
            den_s[wave * 16 + lr] = den;
            float M1 = m1 - sum1 * (1.0f / 100.0f);
            float M2 = m2 - sum2 * (1.0f / 94.0f);
            Mout[bh * L_ + l] = M1 - M2;
        }
        // normalize + coalesced copy-out (within-wave; waitcnt via mem deps)
        for (int f = lane; f < 400; f += 64) {
            int row = f / 25, c = f - row * 25;
            int lg = lt * 16 + row;
            if (lg < 100) {
                f32x4 p = *(const f32x4*)(pbase + row * 400 + c * 16);
                float invd = 1.0f / den_s[wave * 16 + row];
                p.x *= invd; p.y *= invd; p.z *= invd; p.w *= invd;
                *(f32x4*)(series + (bh * L_ + lg) * L_ + c * 4) = p;
            }
        }
    }
}

// ---------------- Kernel C: V = series @ values ----------------
__global__ __launch_bounds__(256) void pv_kernel(
    const float* __restrict__ Vin, const float* __restrict__ series,
    float* __restrict__ Vout) {
    const int bid = blockIdx.x;
    const int b = bid >> 3, h = bid & 7;
    __shared__ float Vl[L_ * D_];    // 25600 B
    __shared__ float Sl[L_ * L_];    // 40000 B
    const int t = threadIdx.x;
    for (int f = t; f < L_ * 16; f += 256) {
        int j = f >> 4, q = f & 15;
        *(float4*)(Vl + j * D_ + q * 4) =
            *(const float4*)(Vin + (((size_t)b * L_ + j) * H_ + h) * D_ + q * 4);
    }
    const float4* srow4 = (const float4*)(series + (size_t)(b * H_ + h) * (L_ * L_));
    for (int f = t; f < L_ * L_ / 4; f += 256)
        *(float4*)(Sl + f * 4) = srow4[f];
    __syncthreads();

    const int wave = __builtin_amdgcn_readfirstlane(t >> 6);
    const int lane = t & 63;  // = d

    for (int i0 = 0; i0 < 25; i0 += 5) {
        const int l0 = wave * 25 + i0;
        float acc[5] = {0.f, 0.f, 0.f, 0.f, 0.f};
#pragma unroll 5
        for (int jb = 0; jb < 25; ++jb) {
            float v0 = Vl[(jb * 4 + 0) * D_ + lane];
            float v1 = Vl[(jb * 4 + 1) * D_ + lane];
            float v2 = Vl[(jb * 4 + 2) * D_ + lane];
            float v3 = Vl[(jb * 4 + 3) * D_ + lane];
#pragma unroll
            for (int r = 0; r < 5; ++r) {
                float4 p = *(const float4*)(Sl + (l0 + r) * L_ + jb * 4);  // broadcast
                acc[r] += p.x * v0 + p.y * v1 + p.z * v2 + p.w * v3;
            }
        }
#pragma unroll
        for (int r = 0; r < 5; ++r)
            Vout[(((size_t)b * L_ + (l0 + r)) * H_ + h) * D_ + lane] = acc[r];
    }
}

extern "C" void kernel_launch(void* const* d_in, const int* in_sizes, int n_in,
                              void* d_out, int out_size, void* d_ws, size_t ws_size,
                              hipStream_t stream) {
    const float* Q     = (const float*)d_in[0];
    const float* K     = (const float*)d_in[1];
    const float* V     = (const float*)d_in[2];
    const float* sigma = (const float*)d_in[3];
    const float* dist  = (const float*)d_in[4];

    float* out    = (float*)d_out;
    float* Vout   = out;
    float* series = out + OFF_SERIES;
    float* prior  = out + OFF_PRIOR;
    float* sigout = out + OFF_SIG;
    float* Mout   = out + OFF_M;

    dim3 grid(B_ * H_), block(256);
    hipLaunchKernelGGL(prior_kernel,  grid, block, 0, stream, sigma, dist, prior, sigout);
    hipLaunchKernelGGL(scores_kernel, grid, block, 0, stream, Q, K, series, Mout);
    hipLaunchKernelGGL(pv_kernel,     grid, block, 0, stream, V, series, Vout);
}